// Round 15
// baseline (891.816 us; speedup 1.0000x reference)
//
#include <hip/hip_runtime.h>
#include <hip/hip_bf16.h>
#include <math.h>

#define BB   16
#define CCH  64
#define NPT  32768
#define RR   32
#define R3   32768
#define GSZ  262144
#define VOXB 2228224   // 32*32*34*64 bf16 elements per batch (z padded to 34)

typedef __attribute__((ext_vector_type(8))) short bfx8;
typedef __attribute__((ext_vector_type(8))) unsigned short usx8;
typedef __attribute__((ext_vector_type(16))) float f32x16;

__device__ __forceinline__ short f2bf(float f) {
    unsigned u = __builtin_bit_cast(unsigned, f);
    u += 0x7fff + ((u >> 16) & 1);
    return (short)(u >> 16);
}
__device__ __forceinline__ float bf2f(unsigned short s) {
    unsigned u = ((unsigned)s) << 16;
    return __builtin_bit_cast(float, u);
}

// ---------------- block reduction helpers -------------------------------------
__device__ __forceinline__ float blockReduceSumF(float v) {
    __shared__ float sm[16];
    #pragma unroll
    for (int o = 32; o > 0; o >>= 1) v += __shfl_down(v, o);
    __syncthreads();
    if ((threadIdx.x & 63) == 0) sm[threadIdx.x >> 6] = v;
    __syncthreads();
    float s = 0.f;
    int nw = blockDim.x >> 6;
    for (int i = 0; i < nw; ++i) s += sm[i];
    return s;
}

__device__ __forceinline__ float blockReduceMaxF(float v) {
    __shared__ float sm[16];
    #pragma unroll
    for (int o = 32; o > 0; o >>= 1) v = fmaxf(v, __shfl_down(v, o));
    __syncthreads();
    if ((threadIdx.x & 63) == 0) sm[threadIdx.x >> 6] = v;
    __syncthreads();
    float s = sm[0];
    int nw = blockDim.x >> 6;
    for (int i = 1; i < nw; ++i) s = fmaxf(s, sm[i]);
    return s;
}

// ---------------- 0. fused zeroing: voxT_in z-pads + hist + st block -----------
__global__ void k_zero(short* __restrict__ voxTin, int* __restrict__ hist,
                       float* __restrict__ stblk) {
    int t = blockIdx.x * 256 + threadIdx.x;
    if (t < 262144) {               // 16b * 1024xy * 2zp * 8q
        int q = t & 7, zp = (t >> 3) & 1, xy = (t >> 4) & 1023, b = t >> 14;
        int z = zp ? 33 : 0;
        *(int4*)(voxTin + (size_t)b * VOXB + ((size_t)xy * 34 + z) * 64 + q * 8) =
            make_int4(0, 0, 0, 0);
    } else if (t < 262144 + 131072) {   // hist 2MB
        ((int4*)hist)[t - 262144] = make_int4(0, 0, 0, 0);
    } else if (t < 262144 + 131072 + 212) {  // st1,st2,stp,csum,cmax = 848 floats
        ((int4*)stblk)[t - 262144 - 131072] = make_int4(0, 0, 0, 0);
    }
}

// ---------------- 1a. coord partial sums (128 blocks) --------------------------
__global__ void k_cstat_sum(const float* __restrict__ coords, float* __restrict__ csum) {
    int b = blockIdx.x >> 3, seg = blockIdx.x & 7;
    const float* cb = coords + (size_t)b * 3 * NPT;
    int n0 = seg << 12;
    float sx = 0.f, sy = 0.f, sz = 0.f;
    for (int n = n0 + threadIdx.x; n < n0 + 4096; n += 256) {
        sx += cb[n]; sy += cb[NPT + n]; sz += cb[2 * NPT + n];
    }
    sx = blockReduceSumF(sx);
    sy = blockReduceSumF(sy);
    sz = blockReduceSumF(sz);
    if (threadIdx.x == 0) {
        atomicAdd(&csum[b * 4 + 0], sx);
        atomicAdd(&csum[b * 4 + 1], sy);
        atomicAdd(&csum[b * 4 + 2], sz);
    }
}

// ---------------- 1b. coord max distance (128 blocks, int-bits atomicMax) ------
__global__ void k_cstat_max(const float* __restrict__ coords, const float* __restrict__ csum,
                            int* __restrict__ cmax) {
    int b = blockIdx.x >> 3, seg = blockIdx.x & 7;
    const float* cb = coords + (size_t)b * 3 * NPT;
    float mx = csum[b * 4 + 0] * (1.f / NPT);
    float my = csum[b * 4 + 1] * (1.f / NPT);
    float mz = csum[b * 4 + 2] * (1.f / NPT);
    int n0 = seg << 12;
    float mn = 0.f;
    for (int n = n0 + threadIdx.x; n < n0 + 4096; n += 256) {
        float x = cb[n] - mx, y = cb[NPT + n] - my, z = cb[2 * NPT + n] - mz;
        mn = fmaxf(mn, sqrtf(x * x + y * y + z * z));
    }
    mn = blockReduceMaxF(mn);
    if (threadIdx.x == 0) atomicMax(&cmax[b], __float_as_int(mn));
}

// ---------------- 2. normalized coords + voxel idx + histogram + passthrough ---
__global__ void k_norm_idx(const float* __restrict__ coords, const float* __restrict__ csum,
                           const int* __restrict__ cmax,
                           float* __restrict__ normc, int* __restrict__ vidx,
                           int* __restrict__ hist, float* __restrict__ out2) {
    int t = blockIdx.x * 256 + threadIdx.x;
    int b = t >> 15, n = t & 32767;
    float mx = csum[b * 4 + 0] * (1.f / NPT);
    float my = csum[b * 4 + 1] * (1.f / NPT);
    float mz = csum[b * 4 + 2] * (1.f / NPT);
    float scale = 2.f * __int_as_float(cmax[b]);
    const float* cb = coords + (size_t)b * 3 * NPT;
    float x = cb[n], y = cb[NPT + n], z = cb[2 * NPT + n];
    float nx = fminf(fmaxf(((x - mx) / scale + 0.5f) * 32.f, 0.f), 31.f);
    float ny = fminf(fmaxf(((y - my) / scale + 0.5f) * 32.f, 0.f), 31.f);
    float nz = fminf(fmaxf(((z - mz) / scale + 0.5f) * 32.f, 0.f), 31.f);
    float* nb = normc + (size_t)b * 3 * NPT;
    nb[n] = nx; nb[NPT + n] = ny; nb[2 * NPT + n] = nz;
    int vx = (int)rintf(nx), vy = (int)rintf(ny), vz = (int)rintf(nz);
    int v = (vx * 32 + vy) * 32 + vz;
    vidx[t] = v;
    atomicAdd(&hist[(b << 15) + v], 1);
    float* o2 = out2 + (size_t)b * 3 * NPT;
    o2[n] = x; o2[NPT + n] = y; o2[2 * NPT + n] = z;
}

// ---------------- 3. per-batch exclusive prefix over 32768 bins ----------------
__global__ __launch_bounds__(1024) void k_prefix(const int* __restrict__ hist,
                                                 int* __restrict__ startB,
                                                 int* __restrict__ base) {
    int b = blockIdx.x;
    int tid = threadIdx.x;
    const int* h = hist + (b << 15);
    int loc[32];
    int s = 0;
    #pragma unroll
    for (int j = 0; j < 32; ++j) { loc[j] = h[tid * 32 + j]; s += loc[j]; }
    __shared__ int sm[1024];
    sm[tid] = s;
    __syncthreads();
    for (int o = 1; o < 1024; o <<= 1) {
        int v = (tid >= o) ? sm[tid - o] : 0;
        __syncthreads();
        sm[tid] += v;
        __syncthreads();
    }
    int run = (tid ? sm[tid - 1] : 0);
    #pragma unroll
    for (int j = 0; j < 32; ++j) {
        int idx = (b << 15) + tid * 32 + j;
        startB[idx] = run;
        base[idx] = run;
        run += loc[j];
    }
}

// ---------------- 4. reorder: feat [b][c][n] f32 -> featT [b][slot][c] bf16 ----
__global__ __launch_bounds__(256) void k_reorder(const float* __restrict__ feat,
                                                 const int* __restrict__ vidx,
                                                 int* __restrict__ base,
                                                 short* __restrict__ featT) {
    __shared__ float tile[64][65];
    __shared__ int sslot[64];
    int blk = blockIdx.x;             // 8192 = 16 b * 512
    int b = blk >> 9;
    int n0 = (blk & 511) << 6;
    int tid = threadIdx.x;
    const float* fb = feat + ((size_t)b << 21);
    for (int e = tid; e < 64 * 16; e += 256) {
        int c = e >> 4, n4 = e & 15;
        float4 v4 = *(const float4*)(fb + ((size_t)c << 15) + n0 + n4 * 4);
        tile[c][n4 * 4 + 0] = v4.x; tile[c][n4 * 4 + 1] = v4.y;
        tile[c][n4 * 4 + 2] = v4.z; tile[c][n4 * 4 + 3] = v4.w;
    }
    if (tid < 64) {
        int v = vidx[(b << 15) + n0 + tid];
        sslot[tid] = atomicAdd(&base[(b << 15) + v], 1);
    }
    __syncthreads();
    int p = tid >> 2, q = tid & 3;    // 4 threads/point, 16 ch each
    int slot = sslot[p];
    short* dst = featT + (((size_t)((b << 15) + slot)) << 6) + q * 16;
    unsigned pk[8];
    #pragma unroll
    for (int k = 0; k < 8; ++k) {
        unsigned lo16 = (unsigned short)f2bf(tile[q * 16 + 2 * k][p]);
        unsigned hi16 = (unsigned short)f2bf(tile[q * 16 + 2 * k + 1][p]);
        pk[k] = lo16 | (hi16 << 16);
    }
    *(int4*)dst = make_int4(pk[0], pk[1], pk[2], pk[3]);
    *(int4*)(dst + 8) = make_int4(pk[4], pk[5], pk[6], pk[7]);
}

// ---------------- 5. voxel accumulate + divide + bf16 padded layout ------------
__global__ void k_vox_accum(const short* __restrict__ featT, const int* __restrict__ startB,
                            const int* __restrict__ base, short* __restrict__ vout) {
    int t = blockIdx.x * 256 + threadIdx.x;   // over B*R3*16
    int lane4 = t & 15;
    int v = (t >> 4) & 32767;
    int b = t >> 19;
    int start = startB[(b << 15) + v];
    int end   = base[(b << 15) + v];
    float4 acc = make_float4(0.f, 0.f, 0.f, 0.f);
    const short* fT = featT + (((size_t)b << 15) << 6) + lane4 * 4;
    for (int p = start; p < end; ++p) {
        short4 hv = *(const short4*)(fT + ((size_t)p << 6));
        acc.x += bf2f((unsigned short)hv.x);
        acc.y += bf2f((unsigned short)hv.y);
        acc.z += bf2f((unsigned short)hv.z);
        acc.w += bf2f((unsigned short)hv.w);
    }
    float rc = 1.f / fmaxf((float)(end - start), 1.f);
    short4 pk;
    pk.x = f2bf(acc.x * rc); pk.y = f2bf(acc.y * rc);
    pk.z = f2bf(acc.z * rc); pk.w = f2bf(acc.w * rc);
    *(short4*)(vout + (size_t)b * VOXB + ((size_t)(v >> 5) * 34 + (v & 31) + 1) * 64 + lane4 * 4) = pk;
}

// ---------------- 6. zero only the z-pad slices of a padded volume -------------
__global__ void k_padzero(short* __restrict__ v) {
    int t = blockIdx.x * 256 + threadIdx.x;   // 262144 = 16b * 1024xy * 2zp * 8q
    int q = t & 7, zp = (t >> 3) & 1, xy = (t >> 4) & 1023, b = t >> 14;
    int z = zp ? 33 : 0;
    *(int4*)(v + (size_t)b * VOXB + ((size_t)xy * 34 + z) * 64 + q * 8) = make_int4(0, 0, 0, 0);
}

// ---------------- 7. weight transpose x2: [co][ci][27] f32 -> [k][co][ci] bf16 -
__global__ void k_wprep2(const float* __restrict__ w1, const float* __restrict__ w2,
                         short* __restrict__ wT1, short* __restrict__ wT2) {
    int e = blockIdx.x * 256 + threadIdx.x;   // 2 * 110592
    const float* w = (e < 110592) ? w1 : w2;
    short* o = (e < 110592) ? wT1 : wT2;
    int ee = (e < 110592) ? e : e - 110592;
    int ci = ee & 63, co = (ee >> 6) & 63, k = ee >> 12;
    o[ee] = f2bf(w[(size_t)(co * 64 + ci) * 27 + k]);
}

// ---------------- 7b. GN affine prep: st sums -> per-(b,c) scale/shift ---------
__global__ void k_gnprep(const float* __restrict__ st, const float* __restrict__ g,
                         const float* __restrict__ be,
                         float* __restrict__ scl, float* __restrict__ sft) {
    int t = blockIdx.x * 256 + threadIdx.x;   // 1024 = 16 b * 64 c
    int b = t >> 6, c = t & 63, cg = c >> 3;
    float s = st[(b * 8 + cg) * 2 + 0], s2 = st[(b * 8 + cg) * 2 + 1];
    float mean = s * (1.f / 262144.f);
    float rstd = rsqrtf(s2 * (1.f / 262144.f) - mean * mean + 1e-5f);
    float gm = g[c];
    scl[t] = gm * rstd;
    sft[t] = be[c] - mean * gm * rstd;
}

// ---------------- 8. MFMA conv: 8 waves = (4 x-lines x 2 j-halves), full co ----
// Each wave: 2 output y-lines x 32z x 64co (acc[2cb][2j], 64 AGPR). Per
// (dx,dz,s): 4 B-line reads feed 12 MFMA (3 per read, vs 2 in the co-half
// split) -> 33% fewer LDS reads. FUSE: table GN+swish on input staging (conv2).
template<bool FUSE>
__global__ __launch_bounds__(512, 4) void k_conv_mfma(
    const short* __restrict__ vin, const short* __restrict__ wT,
    const float* __restrict__ bias,
    const float* __restrict__ scl, const float* __restrict__ sft,
    short* __restrict__ vout, float* __restrict__ st)
{
    __shared__ short lds[36 * 1088];      // 78336 B
    __shared__ float sred[8][2];
    int bid = blockIdx.x;                 // 1024 = 8 xcd * 2 b * 64 tiles
    int xcd = bid & 7, sub = bid >> 3;
    int b = (xcd << 1) | (sub >> 6);
    int tile = sub & 63;
    int x0 = (tile >> 3) << 2, y0 = (tile & 7) << 2;
    int tid = threadIdx.x;
    int wv8 = tid >> 6;
    int jh = wv8 & 1, xl = wv8 >> 1;      // j-half, x-line
    int jbase = jh * 2;
    int l = tid & 63, lo = l & 31, hi = l >> 5;
    const short* vb = vin + (size_t)b * VOXB;
    int xo = x0 + xl;
    if (tid < 16) ((float*)sred)[tid] = 0.f;

    f32x16 acc[2][2];                     // [cb][jj]
    #pragma unroll
    for (int cb = 0; cb < 2; ++cb)
        #pragma unroll
        for (int jj = 0; jj < 2; ++jj)
            #pragma unroll
            for (int i = 0; i < 16; ++i) acc[cb][jj][i] = 0.f;

    #pragma unroll
    for (int h = 0; h < 2; ++h) {
        if (h) __syncthreads();
        for (int e = tid; e < 4896; e += 512) {
            int line = e / 136, r = e - line * 136;
            int z = r >> 2, q = r & 3;
            int xx = line / 6, yy = line - xx * 6;
            int xi = x0 + xx - 1, yi = y0 + yy - 1;
            bool inb = ((unsigned)xi < 32u) && ((unsigned)yi < 32u);
            int4 v = make_int4(0, 0, 0, 0);
            if (inb)
                v = *(const int4*)(vb + ((size_t)(xi * 32 + yi) * 34 + z) * 64 + h * 32 + q * 8);
            if (FUSE) {
                if (inb && z >= 1 && z <= 32) {
                    int ci0 = (b << 6) + h * 32 + q * 8;
                    float4 sa = *(const float4*)(scl + ci0);
                    float4 sb = *(const float4*)(scl + ci0 + 4);
                    float4 fa = *(const float4*)(sft + ci0);
                    float4 fb = *(const float4*)(sft + ci0 + 4);
                    float sv[8] = {sa.x, sa.y, sa.z, sa.w, sb.x, sb.y, sb.z, sb.w};
                    float fv[8] = {fa.x, fa.y, fa.z, fa.w, fb.x, fb.y, fb.z, fb.w};
                    unsigned short* hv = (unsigned short*)&v;
                    #pragma unroll
                    for (int i = 0; i < 8; ++i) {
                        float g = fmaf(bf2f(hv[i]), sv[i], fv[i]);
                        float sw = g / (1.f + __expf(-g));
                        hv[i] = (unsigned short)f2bf(sw);
                    }
                }
            }
            int dst = line * 1088 + z * 32 + ((q * 8) ^ ((z & 3) << 3));
            *(int4*)(lds + dst) = v;
        }
        __syncthreads();
        const short* wbase = wT + lo * 64 + h * 32 + hi * 8;
        #pragma unroll
        for (int dx = 0; dx < 3; ++dx) {
            const short* ldsx = lds + ((xl + dx) * 6 + jbase) * 1088;
            #pragma unroll
            for (int dz = 0; dz < 3; ++dz) {
                int zz = lo + dz;
                int swz = (zz & 3) << 3;
                const short* bcol = ldsx + zz * 32;
                #pragma unroll
                for (int s = 0; s < 2; ++s) {
                    int slot = (s * 16 + hi * 8) ^ swz;
                    bfx8 bv0 = *(const bfx8*)(bcol + 0 * 1088 + slot);
                    bfx8 bv1 = *(const bfx8*)(bcol + 1 * 1088 + slot);
                    bfx8 bv2 = *(const bfx8*)(bcol + 2 * 1088 + slot);
                    bfx8 bv3 = *(const bfx8*)(bcol + 3 * 1088 + slot);
                    const short* wt0 = wbase + (dx * 9 + dz) * 4096 + s * 16;
                    #pragma unroll
                    for (int cb = 0; cb < 2; ++cb) {
                        const short* wc = wt0 + cb * 2048;
                        bfx8 w0 = *(const bfx8*)(wc);
                        bfx8 w1 = *(const bfx8*)(wc + 3 * 4096);
                        bfx8 w2 = *(const bfx8*)(wc + 6 * 4096);
                        acc[cb][0] = __builtin_amdgcn_mfma_f32_32x32x16_bf16(w0, bv0, acc[cb][0], 0, 0, 0);
                        acc[cb][1] = __builtin_amdgcn_mfma_f32_32x32x16_bf16(w0, bv1, acc[cb][1], 0, 0, 0);
                        acc[cb][0] = __builtin_amdgcn_mfma_f32_32x32x16_bf16(w1, bv1, acc[cb][0], 0, 0, 0);
                        acc[cb][1] = __builtin_amdgcn_mfma_f32_32x32x16_bf16(w1, bv2, acc[cb][1], 0, 0, 0);
                        acc[cb][0] = __builtin_amdgcn_mfma_f32_32x32x16_bf16(w2, bv2, acc[cb][0], 0, 0, 0);
                        acc[cb][1] = __builtin_amdgcn_mfma_f32_32x32x16_bf16(w2, bv3, acc[cb][1], 0, 0, 0);
                    }
                }
            }
        }
    }

    // epilogue: bias + bf16 store + fused GN partial sums (2 y-lines, full co)
    float gs[8], gs2[8];
    #pragma unroll
    for (int g = 0; g < 8; ++g) { gs[g] = 0.f; gs2[g] = 0.f; }
    short* ob = vout + (size_t)b * VOXB;
    #pragma unroll
    for (int cb = 0; cb < 2; ++cb) {
        #pragma unroll
        for (int jj = 0; jj < 2; ++jj) {
            size_t rb = ((size_t)(xo * 32 + y0 + jbase + jj) * 34 + 1 + lo) * 64;
            #pragma unroll
            for (int q = 0; q < 4; ++q) {
                int co0 = cb * 32 + hi * 4 + q * 8;
                float v0 = acc[cb][jj][q * 4 + 0] + bias[co0 + 0];
                float v1 = acc[cb][jj][q * 4 + 1] + bias[co0 + 1];
                float v2 = acc[cb][jj][q * 4 + 2] + bias[co0 + 2];
                float v3 = acc[cb][jj][q * 4 + 3] + bias[co0 + 3];
                int g = cb * 4 + q;
                gs[g] += v0 + v1 + v2 + v3;
                gs2[g] += v0 * v0 + v1 * v1 + v2 * v2 + v3 * v3;
                short4 pk;
                pk.x = f2bf(v0); pk.y = f2bf(v1); pk.z = f2bf(v2); pk.w = f2bf(v3);
                *(short4*)(ob + rb + co0) = pk;
            }
        }
    }
    #pragma unroll
    for (int g = 0; g < 8; ++g) {
        float s = gs[g], s2 = gs2[g];
        #pragma unroll
        for (int o = 32; o > 0; o >>= 1) { s += __shfl_down(s, o); s2 += __shfl_down(s2, o); }
        if (l == 0) { atomicAdd(&sred[g][0], s); atomicAdd(&sred[g][1], s2); }
    }
    __syncthreads();
    if (tid < 8) {
        atomicAdd(&st[((b << 3) + tid) * 2 + 0], sred[tid][0]);
        atomicAdd(&st[((b << 3) + tid) * 2 + 1], sred[tid][1]);
    }
}

// ---------------- 9. GN apply + swish (tables), in place on padded volume ------
__global__ void k_gn_apply_b(short* __restrict__ v, const float* __restrict__ scl,
                             const float* __restrict__ sft) {
    int e = blockIdx.x * 256 + threadIdx.x;   // over 16*32768*8
    int cg = e & 7, vx = (e >> 3) & 32767, b = e >> 18;
    int ci0 = (b << 6) + cg * 8;
    float4 sa = *(const float4*)(scl + ci0);
    float4 sb = *(const float4*)(scl + ci0 + 4);
    float4 fa = *(const float4*)(sft + ci0);
    float4 fb = *(const float4*)(sft + ci0 + 4);
    float sv[8] = {sa.x, sa.y, sa.z, sa.w, sb.x, sb.y, sb.z, sb.w};
    float fv[8] = {fa.x, fa.y, fa.z, fa.w, fb.x, fb.y, fb.z, fb.w};
    short* p = v + (size_t)b * VOXB + ((size_t)(vx >> 5) * 34 + (vx & 31) + 1) * 64 + cg * 8;
    usx8 hv = *(const usx8*)p;
    usx8 ov;
    #pragma unroll
    for (int i = 0; i < 8; ++i) {
        float g = fmaf(bf2f(hv[i]), sv[i], fv[i]);
        float sw = g / (1.f + __expf(-g));
        ov[i] = (unsigned short)f2bf(sw);
    }
    *(usx8*)p = ov;
}

// ---------------- 10. point GEMM -> bf16 pre-GN scratch + fused GN stats -------
__global__ __launch_bounds__(256) void k_point(const float* __restrict__ feat,
                                               const float* __restrict__ wp,
                                               const float* __restrict__ bp,
                                               short* __restrict__ pbuf,
                                               float* __restrict__ stp) {
    __shared__ float s_f[64][64];
    __shared__ float s_w[64][68];
    __shared__ float sred[8][2];
    int nblk = blockIdx.x * 64;
    int b = blockIdx.y;
    int tid = threadIdx.x;
    if (tid < 16) ((float*)sred)[tid] = 0.f;
    const float* fb = feat + (((size_t)b * CCH) << 15);
    for (int e = tid; e < 64 * 64; e += 256) {
        int c = e >> 6, nn = e & 63;
        s_f[c][nn] = fb[(((size_t)c) << 15) + nblk + nn];
        s_w[nn][c] = wp[e];
    }
    __syncthreads();
    int o0 = (tid >> 4) << 2;
    int n0 = (tid & 15) << 2;
    float acc[4][4] = {{0.f}};
    for (int c = 0; c < 64; ++c) {
        float4 fv = *(const float4*)&s_f[c][n0];
        float4 wv = *(const float4*)&s_w[c][o0];
        float fvv[4] = {fv.x, fv.y, fv.z, fv.w};
        float wvv[4] = {wv.x, wv.y, wv.z, wv.w};
        #pragma unroll
        for (int j = 0; j < 4; ++j)
            #pragma unroll
            for (int i = 0; i < 4; ++i) acc[j][i] += wvv[j] * fvv[i];
    }
    float s = 0.f, s2 = 0.f;
    #pragma unroll
    for (int j = 0; j < 4; ++j) {
        float bb = bp[o0 + j];
        short* op = pbuf + (((size_t)(b * CCH + o0 + j)) << 15) + nblk + n0;
        short4 pk;
        float v0 = acc[j][0] + bb, v1 = acc[j][1] + bb;
        float v2 = acc[j][2] + bb, v3 = acc[j][3] + bb;
        s += v0 + v1 + v2 + v3;
        s2 += v0 * v0 + v1 * v1 + v2 * v2 + v3 * v3;
        pk.x = f2bf(v0); pk.y = f2bf(v1); pk.z = f2bf(v2); pk.w = f2bf(v3);
        *(short4*)op = pk;
    }
    int g = o0 >> 3;
    atomicAdd(&sred[g][0], s);
    atomicAdd(&sred[g][1], s2);
    __syncthreads();
    if (tid < 8) {
        atomicAdd(&stp[(b * 8 + tid) * 2 + 0], sred[tid][0]);
        atomicAdd(&stp[(b * 8 + tid) * 2 + 1], sred[tid][1]);
    }
}

// ---------------- 11. final: devox gather + point GN/swish + add ---------------
__global__ void k_final(const short* __restrict__ h, const float* __restrict__ normc,
                        const float* __restrict__ stp, const float* __restrict__ gp,
                        const float* __restrict__ bep, const short* __restrict__ pbuf,
                        float* __restrict__ out1) {
    int tid = threadIdx.x;
    int s = tid & 7, pp = tid >> 3;
    int pt = blockIdx.x * 32 + pp;
    int b = pt >> 15, n = pt & 32767;
    const float* nb = normc + (size_t)b * 3 * NPT;
    float nx = nb[n], ny = nb[NPT + n], nz = nb[2 * NPT + n];
    float fxf = floorf(nx), fyf = floorf(ny), fzf = floorf(nz);
    float fx = nx - fxf, fy = ny - fyf, fz = nz - fzf;
    int x0 = (int)fxf; x0 = x0 < 31 ? x0 : 31;
    int y0 = (int)fyf; y0 = y0 < 31 ? y0 : 31;
    int z0 = (int)fzf; z0 = z0 < 31 ? z0 : 31;
    int x1 = x0 + 1 < 31 ? x0 + 1 : 31;
    int y1 = y0 + 1 < 31 ? y0 + 1 : 31;
    int z1 = z0 + 1 < 31 ? z0 + 1 : 31;
    float wx0 = 1.f - fx, wx1 = fx, wy0 = 1.f - fy, wy1 = fy, wz0 = 1.f - fz, wz1 = fz;
    const short* hb = h + (size_t)b * VOXB + s * 8;
    float acc[8];
    #pragma unroll
    for (int i = 0; i < 8; ++i) acc[i] = 0.f;
    #pragma unroll
    for (int cx = 0; cx < 2; ++cx) {
        int xi = cx ? x1 : x0; float wxx = cx ? wx1 : wx0;
        #pragma unroll
        for (int cy = 0; cy < 2; ++cy) {
            int yi = cy ? y1 : y0; float wyy = cy ? wy1 : wy0;
            #pragma unroll
            for (int cz = 0; cz < 2; ++cz) {
                int zi = cz ? z1 : z0; float wzz = cz ? wz1 : wz0;
                float w = wxx * wyy * wzz;
                usx8 hv = *(const usx8*)(hb + ((size_t)(xi * 32 + yi) * 34 + zi + 1) * 64);
                #pragma unroll
                for (int i = 0; i < 8; ++i) acc[i] = fmaf(w, bf2f(hv[i]), acc[i]);
            }
        }
    }
    float ss = stp[(b * 8 + s) * 2 + 0], ss2 = stp[(b * 8 + s) * 2 + 1];
    float mean = ss * (1.f / 262144.f);
    float rstd = rsqrtf(ss2 * (1.f / 262144.f) - mean * mean + 1e-5f);
    const short* pb = pbuf + (((size_t)(b * CCH)) << 15) + n;
    #pragma unroll
    for (int i = 0; i < 8; ++i) {
        int co = s * 8 + i;
        float* op = out1 + (((size_t)(b * CCH + co)) << 15) + n;
        float pv = bf2f((unsigned short)pb[((size_t)co) << 15]);
        float g = (pv - mean) * rstd * gp[co] + bep[co];
        float sw = g / (1.f + __expf(-g));
        *op = acc[i] + sw;
    }
}

// --------------------------------- launcher ------------------------------------
extern "C" void kernel_launch(void* const* d_in, const int* in_sizes, int n_in,
                              void* d_out, int out_size, void* d_ws, size_t ws_size,
                              hipStream_t stream) {
    const float* feat   = (const float*)d_in[0];
    const float* coords = (const float*)d_in[1];
    const float* w1  = (const float*)d_in[2];
    const float* b1  = (const float*)d_in[3];
    const float* g1  = (const float*)d_in[4];
    const float* be1 = (const float*)d_in[5];
    const float* w2  = (const float*)d_in[6];
    const float* b2  = (const float*)d_in[7];
    const float* g2  = (const float*)d_in[8];
    const float* be2 = (const float*)d_in[9];
    const float* wp  = (const float*)d_in[10];
    const float* bp  = (const float*)d_in[11];
    const float* gp  = (const float*)d_in[12];
    const float* bep = (const float*)d_in[13];

    float* out1 = (float*)d_out;
    float* out2 = out1 + (size_t)BB * CCH * NPT;

    // workspace layout (~216 MB)
    // region0 [0, 134MB): featT bf16 (67MB) -> voxT_mid bf16 (71MB) -> pbuf bf16 (67MB)
    const size_t reg0Bytes = (size_t)BB * NPT * CCH * 4;
    short* featT    = (short*)d_ws;
    short* voxT_mid = (short*)d_ws;
    short* pbuf     = (short*)d_ws;
    short* voxT_in  = (short*)((char*)d_ws + reg0Bytes);
    char* p = (char*)voxT_in + (size_t)BB * VOXB * 2;
    int*   hist   = (int*)p;  p += (size_t)BB * R3 * 4;
    int*   startB = (int*)p;  p += (size_t)BB * R3 * 4;
    int*   base   = (int*)p;  p += (size_t)BB * R3 * 4;
    float* normc = (float*)p; p += (size_t)BB * 3 * NPT * 4;
    int*   vidx  = (int*)p;   p += (size_t)BB * NPT * 4;
    short* wT1   = (short*)p; p += 110592 * 2;
    short* wT2   = (short*)p; p += 110592 * 2;
    float* st1   = (float*)p; p += 256 * 4;
    float* st2   = (float*)p; p += 256 * 4;
    float* stp   = (float*)p; p += 256 * 4;
    float* csum  = (float*)p; p += 64 * 4;
    int*   cmax  = (int*)p;   p += 16 * 4;
    float* scl1  = (float*)p; p += 1024 * 4;
    float* sft1  = (float*)p; p += 1024 * 4;
    float* scl2  = (float*)p; p += 1024 * 4;
    float* sft2  = (float*)p; p += 1024 * 4;

    // fused zeroing: voxT_in pads + hist + st1..cmax block (848 floats)
    k_zero<<<1537, 256, 0, stream>>>(voxT_in, hist, st1);
    k_wprep2<<<864, 256, 0, stream>>>(w1, w2, wT1, wT2);
    k_cstat_sum<<<128, 256, 0, stream>>>(coords, csum);
    k_cstat_max<<<128, 256, 0, stream>>>(coords, csum, cmax);
    k_norm_idx<<<(BB * NPT) / 256, 256, 0, stream>>>(coords, csum, cmax, normc, vidx, hist, out2);
    k_prefix<<<BB, 1024, 0, stream>>>(hist, startB, base);
    k_reorder<<<(BB * NPT) / 64, 256, 0, stream>>>(feat, vidx, base, featT);
    k_vox_accum<<<(BB * R3 * 16) / 256, 256, 0, stream>>>(featT, startB, base, voxT_in);

    // featT dead -> region0 becomes voxT_mid; zero only its z-pads
    k_padzero<<<1024, 256, 0, stream>>>(voxT_mid);

    // conv1 -> voxT_mid holds PRE-GN conv1 output + st1 sums
    k_conv_mfma<false><<<1024, 512, 0, stream>>>(voxT_in, wT1, b1,
                                                 nullptr, nullptr, voxT_mid, st1);
    k_gnprep<<<4, 256, 0, stream>>>(st1, g1, be1, scl1, sft1);
    // conv2: staging applies GN1+swish (tables) -> voxT_in (PRE-GN2), st2 sums
    k_conv_mfma<true><<<1024, 512, 0, stream>>>(voxT_mid, wT2, b2,
                                                scl1, sft1, voxT_in, st2);
    k_gnprep<<<4, 256, 0, stream>>>(st2, g2, be2, scl2, sft2);
    // GN2 apply+swish in place (table-based)
    k_gn_apply_b<<<(BB * R3 * 8) / 256, 256, 0, stream>>>(voxT_in, scl2, sft2);

    // voxT_mid dead -> region0 becomes pbuf
    k_point<<<dim3(NPT / 64, BB), 256, 0, stream>>>(feat, wp, bp, pbuf, stp);

    k_final<<<(BB * NPT) / 32, 256, 0, stream>>>(voxT_in, normc, stp, gp, bep, pbuf, out1);
}

// Round 16
// 706.815 us; speedup vs baseline: 1.2617x; 1.2617x over previous
//
#include <hip/hip_runtime.h>
#include <hip/hip_bf16.h>
#include <math.h>

#define BB   16
#define CCH  64
#define NPT  32768
#define RR   32
#define R3   32768
#define GSZ  262144
#define VOXB 2228224   // 32*32*34*64 bf16 elements per batch (z padded to 34)

typedef __attribute__((ext_vector_type(8))) short bfx8;
typedef __attribute__((ext_vector_type(8))) unsigned short usx8;
typedef __attribute__((ext_vector_type(16))) float f32x16;

__device__ __forceinline__ short f2bf(float f) {
    unsigned u = __builtin_bit_cast(unsigned, f);
    u += 0x7fff + ((u >> 16) & 1);
    return (short)(u >> 16);
}
__device__ __forceinline__ float bf2f(unsigned short s) {
    unsigned u = ((unsigned)s) << 16;
    return __builtin_bit_cast(float, u);
}

// ---------------- block reduction helpers -------------------------------------
__device__ __forceinline__ float blockReduceSumF(float v) {
    __shared__ float sm[16];
    #pragma unroll
    for (int o = 32; o > 0; o >>= 1) v += __shfl_down(v, o);
    __syncthreads();
    if ((threadIdx.x & 63) == 0) sm[threadIdx.x >> 6] = v;
    __syncthreads();
    float s = 0.f;
    int nw = blockDim.x >> 6;
    for (int i = 0; i < nw; ++i) s += sm[i];
    return s;
}

__device__ __forceinline__ float blockReduceMaxF(float v) {
    __shared__ float sm[16];
    #pragma unroll
    for (int o = 32; o > 0; o >>= 1) v = fmaxf(v, __shfl_down(v, o));
    __syncthreads();
    if ((threadIdx.x & 63) == 0) sm[threadIdx.x >> 6] = v;
    __syncthreads();
    float s = sm[0];
    int nw = blockDim.x >> 6;
    for (int i = 1; i < nw; ++i) s = fmaxf(s, sm[i]);
    return s;
}

// ---------------- 0. fused zeroing: voxT_in z-pads + hist + st block -----------
__global__ void k_zero(short* __restrict__ voxTin, int* __restrict__ hist,
                       float* __restrict__ stblk) {
    int t = blockIdx.x * 256 + threadIdx.x;
    if (t < 262144) {               // 16b * 1024xy * 2zp * 8q
        int q = t & 7, zp = (t >> 3) & 1, xy = (t >> 4) & 1023, b = t >> 14;
        int z = zp ? 33 : 0;
        *(int4*)(voxTin + (size_t)b * VOXB + ((size_t)xy * 34 + z) * 64 + q * 8) =
            make_int4(0, 0, 0, 0);
    } else if (t < 262144 + 131072) {   // hist 2MB
        ((int4*)hist)[t - 262144] = make_int4(0, 0, 0, 0);
    } else if (t < 262144 + 131072 + 212) {  // st1,st2,stp,csum,cmax = 848 floats
        ((int4*)stblk)[t - 262144 - 131072] = make_int4(0, 0, 0, 0);
    }
}

// ---------------- 1a. coord partial sums (128 blocks) --------------------------
__global__ void k_cstat_sum(const float* __restrict__ coords, float* __restrict__ csum) {
    int b = blockIdx.x >> 3, seg = blockIdx.x & 7;
    const float* cb = coords + (size_t)b * 3 * NPT;
    int n0 = seg << 12;
    float sx = 0.f, sy = 0.f, sz = 0.f;
    for (int n = n0 + threadIdx.x; n < n0 + 4096; n += 256) {
        sx += cb[n]; sy += cb[NPT + n]; sz += cb[2 * NPT + n];
    }
    sx = blockReduceSumF(sx);
    sy = blockReduceSumF(sy);
    sz = blockReduceSumF(sz);
    if (threadIdx.x == 0) {
        atomicAdd(&csum[b * 4 + 0], sx);
        atomicAdd(&csum[b * 4 + 1], sy);
        atomicAdd(&csum[b * 4 + 2], sz);
    }
}

// ---------------- 1b. coord max distance (128 blocks, int-bits atomicMax) ------
__global__ void k_cstat_max(const float* __restrict__ coords, const float* __restrict__ csum,
                            int* __restrict__ cmax) {
    int b = blockIdx.x >> 3, seg = blockIdx.x & 7;
    const float* cb = coords + (size_t)b * 3 * NPT;
    float mx = csum[b * 4 + 0] * (1.f / NPT);
    float my = csum[b * 4 + 1] * (1.f / NPT);
    float mz = csum[b * 4 + 2] * (1.f / NPT);
    int n0 = seg << 12;
    float mn = 0.f;
    for (int n = n0 + threadIdx.x; n < n0 + 4096; n += 256) {
        float x = cb[n] - mx, y = cb[NPT + n] - my, z = cb[2 * NPT + n] - mz;
        mn = fmaxf(mn, sqrtf(x * x + y * y + z * z));
    }
    mn = blockReduceMaxF(mn);
    if (threadIdx.x == 0) atomicMax(&cmax[b], __float_as_int(mn));
}

// ---------------- 2. normalized coords + voxel idx + histogram + passthrough ---
__global__ void k_norm_idx(const float* __restrict__ coords, const float* __restrict__ csum,
                           const int* __restrict__ cmax,
                           float* __restrict__ normc, int* __restrict__ vidx,
                           int* __restrict__ hist, float* __restrict__ out2) {
    int t = blockIdx.x * 256 + threadIdx.x;
    int b = t >> 15, n = t & 32767;
    float mx = csum[b * 4 + 0] * (1.f / NPT);
    float my = csum[b * 4 + 1] * (1.f / NPT);
    float mz = csum[b * 4 + 2] * (1.f / NPT);
    float scale = 2.f * __int_as_float(cmax[b]);
    const float* cb = coords + (size_t)b * 3 * NPT;
    float x = cb[n], y = cb[NPT + n], z = cb[2 * NPT + n];
    float nx = fminf(fmaxf(((x - mx) / scale + 0.5f) * 32.f, 0.f), 31.f);
    float ny = fminf(fmaxf(((y - my) / scale + 0.5f) * 32.f, 0.f), 31.f);
    float nz = fminf(fmaxf(((z - mz) / scale + 0.5f) * 32.f, 0.f), 31.f);
    float* nb = normc + (size_t)b * 3 * NPT;
    nb[n] = nx; nb[NPT + n] = ny; nb[2 * NPT + n] = nz;
    int vx = (int)rintf(nx), vy = (int)rintf(ny), vz = (int)rintf(nz);
    int v = (vx * 32 + vy) * 32 + vz;
    vidx[t] = v;
    atomicAdd(&hist[(b << 15) + v], 1);
    float* o2 = out2 + (size_t)b * 3 * NPT;
    o2[n] = x; o2[NPT + n] = y; o2[2 * NPT + n] = z;
}

// ---------------- 3. per-batch exclusive prefix over 32768 bins ----------------
__global__ __launch_bounds__(1024) void k_prefix(const int* __restrict__ hist,
                                                 int* __restrict__ startB,
                                                 int* __restrict__ base) {
    int b = blockIdx.x;
    int tid = threadIdx.x;
    const int* h = hist + (b << 15);
    int loc[32];
    int s = 0;
    #pragma unroll
    for (int j = 0; j < 32; ++j) { loc[j] = h[tid * 32 + j]; s += loc[j]; }
    __shared__ int sm[1024];
    sm[tid] = s;
    __syncthreads();
    for (int o = 1; o < 1024; o <<= 1) {
        int v = (tid >= o) ? sm[tid - o] : 0;
        __syncthreads();
        sm[tid] += v;
        __syncthreads();
    }
    int run = (tid ? sm[tid - 1] : 0);
    #pragma unroll
    for (int j = 0; j < 32; ++j) {
        int idx = (b << 15) + tid * 32 + j;
        startB[idx] = run;
        base[idx] = run;
        run += loc[j];
    }
}

// ---------------- 4. reorder: feat [b][c][n] f32 -> featT [b][slot][c] bf16 ----
__global__ __launch_bounds__(256) void k_reorder(const float* __restrict__ feat,
                                                 const int* __restrict__ vidx,
                                                 int* __restrict__ base,
                                                 short* __restrict__ featT) {
    __shared__ float tile[64][65];
    __shared__ int sslot[64];
    int blk = blockIdx.x;             // 8192 = 16 b * 512
    int b = blk >> 9;
    int n0 = (blk & 511) << 6;
    int tid = threadIdx.x;
    const float* fb = feat + ((size_t)b << 21);
    for (int e = tid; e < 64 * 16; e += 256) {
        int c = e >> 4, n4 = e & 15;
        float4 v4 = *(const float4*)(fb + ((size_t)c << 15) + n0 + n4 * 4);
        tile[c][n4 * 4 + 0] = v4.x; tile[c][n4 * 4 + 1] = v4.y;
        tile[c][n4 * 4 + 2] = v4.z; tile[c][n4 * 4 + 3] = v4.w;
    }
    if (tid < 64) {
        int v = vidx[(b << 15) + n0 + tid];
        sslot[tid] = atomicAdd(&base[(b << 15) + v], 1);
    }
    __syncthreads();
    int p = tid >> 2, q = tid & 3;    // 4 threads/point, 16 ch each
    int slot = sslot[p];
    short* dst = featT + (((size_t)((b << 15) + slot)) << 6) + q * 16;
    unsigned pk[8];
    #pragma unroll
    for (int k = 0; k < 8; ++k) {
        unsigned lo16 = (unsigned short)f2bf(tile[q * 16 + 2 * k][p]);
        unsigned hi16 = (unsigned short)f2bf(tile[q * 16 + 2 * k + 1][p]);
        pk[k] = lo16 | (hi16 << 16);
    }
    *(int4*)dst = make_int4(pk[0], pk[1], pk[2], pk[3]);
    *(int4*)(dst + 8) = make_int4(pk[4], pk[5], pk[6], pk[7]);
}

// ---------------- 5. voxel accumulate + divide + bf16 padded layout ------------
__global__ void k_vox_accum(const short* __restrict__ featT, const int* __restrict__ startB,
                            const int* __restrict__ base, short* __restrict__ vout) {
    int t = blockIdx.x * 256 + threadIdx.x;   // over B*R3*16
    int lane4 = t & 15;
    int v = (t >> 4) & 32767;
    int b = t >> 19;
    int start = startB[(b << 15) + v];
    int end   = base[(b << 15) + v];
    float4 acc = make_float4(0.f, 0.f, 0.f, 0.f);
    const short* fT = featT + (((size_t)b << 15) << 6) + lane4 * 4;
    for (int p = start; p < end; ++p) {
        short4 hv = *(const short4*)(fT + ((size_t)p << 6));
        acc.x += bf2f((unsigned short)hv.x);
        acc.y += bf2f((unsigned short)hv.y);
        acc.z += bf2f((unsigned short)hv.z);
        acc.w += bf2f((unsigned short)hv.w);
    }
    float rc = 1.f / fmaxf((float)(end - start), 1.f);
    short4 pk;
    pk.x = f2bf(acc.x * rc); pk.y = f2bf(acc.y * rc);
    pk.z = f2bf(acc.z * rc); pk.w = f2bf(acc.w * rc);
    *(short4*)(vout + (size_t)b * VOXB + ((size_t)(v >> 5) * 34 + (v & 31) + 1) * 64 + lane4 * 4) = pk;
}

// ---------------- 6. zero only the z-pad slices of a padded volume -------------
__global__ void k_padzero(short* __restrict__ v) {
    int t = blockIdx.x * 256 + threadIdx.x;   // 262144 = 16b * 1024xy * 2zp * 8q
    int q = t & 7, zp = (t >> 3) & 1, xy = (t >> 4) & 1023, b = t >> 14;
    int z = zp ? 33 : 0;
    *(int4*)(v + (size_t)b * VOXB + ((size_t)xy * 34 + z) * 64 + q * 8) = make_int4(0, 0, 0, 0);
}

// ---------------- 7. weight transpose x2: [co][ci][27] f32 -> [k][co][ci] bf16 -
__global__ void k_wprep2(const float* __restrict__ w1, const float* __restrict__ w2,
                         short* __restrict__ wT1, short* __restrict__ wT2) {
    int e = blockIdx.x * 256 + threadIdx.x;   // 2 * 110592
    const float* w = (e < 110592) ? w1 : w2;
    short* o = (e < 110592) ? wT1 : wT2;
    int ee = (e < 110592) ? e : e - 110592;
    int ci = ee & 63, co = (ee >> 6) & 63, k = ee >> 12;
    o[ee] = f2bf(w[(size_t)(co * 64 + ci) * 27 + k]);
}

// ---------------- 7b. GN affine prep: st sums -> per-(b,c) scale/shift ---------
__global__ void k_gnprep(const float* __restrict__ st, const float* __restrict__ g,
                         const float* __restrict__ be,
                         float* __restrict__ scl, float* __restrict__ sft) {
    int t = blockIdx.x * 256 + threadIdx.x;   // 1024 = 16 b * 64 c
    int b = t >> 6, c = t & 63, cg = c >> 3;
    float s = st[(b * 8 + cg) * 2 + 0], s2 = st[(b * 8 + cg) * 2 + 1];
    float mean = s * (1.f / 262144.f);
    float rstd = rsqrtf(s2 * (1.f / 262144.f) - mean * mean + 1e-5f);
    float gm = g[c];
    scl[t] = gm * rstd;
    sft[t] = be[c] - mean * gm * rstd;
}

// ---------------- 8. MFMA implicit-GEMM conv (r8 shape), FUSE via tables -------
// 512 threads = 8 waves = (2 co-halves x 4 x-lines). Per wave: acc[4] f32x16
// (64 AGPR) -> 16 waves/CU resident. FUSE: apply precomputed per-(b,c)
// scale/shift + swish to input during staging (conv2). Epilogue GN stats -> st.
template<bool FUSE>
__global__ __launch_bounds__(512, 4) void k_conv_mfma(
    const short* __restrict__ vin, const short* __restrict__ wT,
    const float* __restrict__ bias,
    const float* __restrict__ scl, const float* __restrict__ sft,
    short* __restrict__ vout, float* __restrict__ st)
{
    __shared__ short lds[36 * 1088];      // 78336 B
    __shared__ float sred[8][2];
    int bid = blockIdx.x;                 // 1024 = 8 xcd * 2 b * 64 tiles
    int xcd = bid & 7, sub = bid >> 3;
    int b = (xcd << 1) | (sub >> 6);
    int tile = sub & 63;
    int x0 = (tile >> 3) << 2, y0 = (tile & 7) << 2;
    int tid = threadIdx.x;
    int wv8 = tid >> 6;
    int cb = wv8 & 1, xl = wv8 >> 1;      // co-half, x-line
    int l = tid & 63, lo = l & 31, hi = l >> 5;
    const short* vb = vin + (size_t)b * VOXB;
    int xo = x0 + xl;
    if (tid < 16) ((float*)sred)[tid] = 0.f;

    f32x16 acc[4];
    #pragma unroll
    for (int j = 0; j < 4; ++j)
        #pragma unroll
        for (int i = 0; i < 16; ++i) acc[j][i] = 0.f;

    #pragma unroll
    for (int h = 0; h < 2; ++h) {
        if (h) __syncthreads();
        for (int e = tid; e < 4896; e += 512) {
            int line = e / 136, r = e - line * 136;
            int z = r >> 2, q = r & 3;
            int xx = line / 6, yy = line - xx * 6;
            int xi = x0 + xx - 1, yi = y0 + yy - 1;
            bool inb = ((unsigned)xi < 32u) && ((unsigned)yi < 32u);
            int4 v = make_int4(0, 0, 0, 0);
            if (inb)
                v = *(const int4*)(vb + ((size_t)(xi * 32 + yi) * 34 + z) * 64 + h * 32 + q * 8);
            if (FUSE) {
                if (inb && z >= 1 && z <= 32) {
                    int ci0 = (b << 6) + h * 32 + q * 8;
                    float4 sa = *(const float4*)(scl + ci0);
                    float4 sb = *(const float4*)(scl + ci0 + 4);
                    float4 fa = *(const float4*)(sft + ci0);
                    float4 fb = *(const float4*)(sft + ci0 + 4);
                    float sv[8] = {sa.x, sa.y, sa.z, sa.w, sb.x, sb.y, sb.z, sb.w};
                    float fv[8] = {fa.x, fa.y, fa.z, fa.w, fb.x, fb.y, fb.z, fb.w};
                    unsigned short* hv = (unsigned short*)&v;
                    #pragma unroll
                    for (int i = 0; i < 8; ++i) {
                        float g = fmaf(bf2f(hv[i]), sv[i], fv[i]);
                        float sw = g / (1.f + __expf(-g));
                        hv[i] = (unsigned short)f2bf(sw);
                    }
                }
            }
            int dst = line * 1088 + z * 32 + ((q * 8) ^ ((z & 3) << 3));
            *(int4*)(lds + dst) = v;
        }
        __syncthreads();
        const short* wbase = wT + lo * 64 + h * 32 + hi * 8 + cb * 2048;
        #pragma unroll
        for (int dx = 0; dx < 3; ++dx) {
            const short* ldsx = lds + ((xl + dx) * 6) * 1088;
            #pragma unroll
            for (int dz = 0; dz < 3; ++dz) {
                int zz = lo + dz;
                int swz = (zz & 3) << 3;
                const short* bcol = ldsx + zz * 32;
                #pragma unroll
                for (int s = 0; s < 2; ++s) {
                    int slot = (s * 16 + hi * 8) ^ swz;
                    const short* wt0 = wbase + (dx * 9 + dz) * 4096 + s * 16;
                    bfx8 w0 = *(const bfx8*)(wt0);
                    bfx8 w1 = *(const bfx8*)(wt0 + 3 * 4096);
                    bfx8 w2 = *(const bfx8*)(wt0 + 6 * 4096);
                    #pragma unroll
                    for (int L = 0; L < 6; ++L) {
                        bfx8 bv = *(const bfx8*)(bcol + L * 1088 + slot);
                        if (L <= 3)
                            acc[L] = __builtin_amdgcn_mfma_f32_32x32x16_bf16(w0, bv, acc[L], 0, 0, 0);
                        if (L >= 1 && L <= 4)
                            acc[L-1] = __builtin_amdgcn_mfma_f32_32x32x16_bf16(w1, bv, acc[L-1], 0, 0, 0);
                        if (L >= 2)
                            acc[L-2] = __builtin_amdgcn_mfma_f32_32x32x16_bf16(w2, bv, acc[L-2], 0, 0, 0);
                    }
                }
            }
        }
    }

    // epilogue: bias + bf16 store + fused GN partial sums (this wave's co-half)
    float gs[4], gs2[4];
    #pragma unroll
    for (int g = 0; g < 4; ++g) { gs[g] = 0.f; gs2[g] = 0.f; }
    short* ob = vout + (size_t)b * VOXB;
    #pragma unroll
    for (int j = 0; j < 4; ++j) {
        size_t rb = ((size_t)(xo * 32 + y0 + j) * 34 + 1 + lo) * 64;
        #pragma unroll
        for (int q = 0; q < 4; ++q) {
            int co0 = cb * 32 + hi * 4 + q * 8;
            float v0 = acc[j][q * 4 + 0] + bias[co0 + 0];
            float v1 = acc[j][q * 4 + 1] + bias[co0 + 1];
            float v2 = acc[j][q * 4 + 2] + bias[co0 + 2];
            float v3 = acc[j][q * 4 + 3] + bias[co0 + 3];
            gs[q] += v0 + v1 + v2 + v3;
            gs2[q] += v0 * v0 + v1 * v1 + v2 * v2 + v3 * v3;
            short4 pk;
            pk.x = f2bf(v0); pk.y = f2bf(v1); pk.z = f2bf(v2); pk.w = f2bf(v3);
            *(short4*)(ob + rb + co0) = pk;
        }
    }
    #pragma unroll
    for (int q = 0; q < 4; ++q) {
        float s = gs[q], s2 = gs2[q];
        #pragma unroll
        for (int o = 32; o > 0; o >>= 1) { s += __shfl_down(s, o); s2 += __shfl_down(s2, o); }
        if (l == 0) { atomicAdd(&sred[cb * 4 + q][0], s); atomicAdd(&sred[cb * 4 + q][1], s2); }
    }
    __syncthreads();
    if (tid < 8) {
        atomicAdd(&st[((b << 3) + tid) * 2 + 0], sred[tid][0]);
        atomicAdd(&st[((b << 3) + tid) * 2 + 1], sred[tid][1]);
    }
}

// ---------------- 9. GN apply + swish (tables), in place on padded volume ------
__global__ void k_gn_apply_b(short* __restrict__ v, const float* __restrict__ scl,
                             const float* __restrict__ sft) {
    int e = blockIdx.x * 256 + threadIdx.x;   // over 16*32768*8
    int cg = e & 7, vx = (e >> 3) & 32767, b = e >> 18;
    int ci0 = (b << 6) + cg * 8;
    float4 sa = *(const float4*)(scl + ci0);
    float4 sb = *(const float4*)(scl + ci0 + 4);
    float4 fa = *(const float4*)(sft + ci0);
    float4 fb = *(const float4*)(sft + ci0 + 4);
    float sv[8] = {sa.x, sa.y, sa.z, sa.w, sb.x, sb.y, sb.z, sb.w};
    float fv[8] = {fa.x, fa.y, fa.z, fa.w, fb.x, fb.y, fb.z, fb.w};
    short* p = v + (size_t)b * VOXB + ((size_t)(vx >> 5) * 34 + (vx & 31) + 1) * 64 + cg * 8;
    usx8 hv = *(const usx8*)p;
    usx8 ov;
    #pragma unroll
    for (int i = 0; i < 8; ++i) {
        float g = fmaf(bf2f(hv[i]), sv[i], fv[i]);
        float sw = g / (1.f + __expf(-g));
        ov[i] = (unsigned short)f2bf(sw);
    }
    *(usx8*)p = ov;
}

// ---------------- 10. point GEMM -> bf16 pre-GN scratch + fused GN stats -------
__global__ __launch_bounds__(256) void k_point(const float* __restrict__ feat,
                                               const float* __restrict__ wp,
                                               const float* __restrict__ bp,
                                               short* __restrict__ pbuf,
                                               float* __restrict__ stp) {
    __shared__ float s_f[64][64];
    __shared__ float s_w[64][68];
    __shared__ float sred[8][2];
    int nblk = blockIdx.x * 64;
    int b = blockIdx.y;
    int tid = threadIdx.x;
    if (tid < 16) ((float*)sred)[tid] = 0.f;
    const float* fb = feat + (((size_t)b * CCH) << 15);
    for (int e = tid; e < 64 * 64; e += 256) {
        int c = e >> 6, nn = e & 63;
        s_f[c][nn] = fb[(((size_t)c) << 15) + nblk + nn];
        s_w[nn][c] = wp[e];
    }
    __syncthreads();
    int o0 = (tid >> 4) << 2;
    int n0 = (tid & 15) << 2;
    float acc[4][4] = {{0.f}};
    for (int c = 0; c < 64; ++c) {
        float4 fv = *(const float4*)&s_f[c][n0];
        float4 wv = *(const float4*)&s_w[c][o0];
        float fvv[4] = {fv.x, fv.y, fv.z, fv.w};
        float wvv[4] = {wv.x, wv.y, wv.z, wv.w};
        #pragma unroll
        for (int j = 0; j < 4; ++j)
            #pragma unroll
            for (int i = 0; i < 4; ++i) acc[j][i] += wvv[j] * fvv[i];
    }
    float s = 0.f, s2 = 0.f;
    #pragma unroll
    for (int j = 0; j < 4; ++j) {
        float bb = bp[o0 + j];
        short* op = pbuf + (((size_t)(b * CCH + o0 + j)) << 15) + nblk + n0;
        short4 pk;
        float v0 = acc[j][0] + bb, v1 = acc[j][1] + bb;
        float v2 = acc[j][2] + bb, v3 = acc[j][3] + bb;
        s += v0 + v1 + v2 + v3;
        s2 += v0 * v0 + v1 * v1 + v2 * v2 + v3 * v3;
        pk.x = f2bf(v0); pk.y = f2bf(v1); pk.z = f2bf(v2); pk.w = f2bf(v3);
        *(short4*)op = pk;
    }
    int g = o0 >> 3;
    atomicAdd(&sred[g][0], s);
    atomicAdd(&sred[g][1], s2);
    __syncthreads();
    if (tid < 8) {
        atomicAdd(&stp[(b * 8 + tid) * 2 + 0], sred[tid][0]);
        atomicAdd(&stp[(b * 8 + tid) * 2 + 1], sred[tid][1]);
    }
}

// ---------------- 11. final: devox gather + point GN/swish + add ---------------
__global__ void k_final(const short* __restrict__ h, const float* __restrict__ normc,
                        const float* __restrict__ stp, const float* __restrict__ gp,
                        const float* __restrict__ bep, const short* __restrict__ pbuf,
                        float* __restrict__ out1) {
    int tid = threadIdx.x;
    int s = tid & 7, pp = tid >> 3;
    int pt = blockIdx.x * 32 + pp;
    int b = pt >> 15, n = pt & 32767;
    const float* nb = normc + (size_t)b * 3 * NPT;
    float nx = nb[n], ny = nb[NPT + n], nz = nb[2 * NPT + n];
    float fxf = floorf(nx), fyf = floorf(ny), fzf = floorf(nz);
    float fx = nx - fxf, fy = ny - fyf, fz = nz - fzf;
    int x0 = (int)fxf; x0 = x0 < 31 ? x0 : 31;
    int y0 = (int)fyf; y0 = y0 < 31 ? y0 : 31;
    int z0 = (int)fzf; z0 = z0 < 31 ? z0 : 31;
    int x1 = x0 + 1 < 31 ? x0 + 1 : 31;
    int y1 = y0 + 1 < 31 ? y0 + 1 : 31;
    int z1 = z0 + 1 < 31 ? z0 + 1 : 31;
    float wx0 = 1.f - fx, wx1 = fx, wy0 = 1.f - fy, wy1 = fy, wz0 = 1.f - fz, wz1 = fz;
    const short* hb = h + (size_t)b * VOXB + s * 8;
    float acc[8];
    #pragma unroll
    for (int i = 0; i < 8; ++i) acc[i] = 0.f;
    #pragma unroll
    for (int cx = 0; cx < 2; ++cx) {
        int xi = cx ? x1 : x0; float wxx = cx ? wx1 : wx0;
        #pragma unroll
        for (int cy = 0; cy < 2; ++cy) {
            int yi = cy ? y1 : y0; float wyy = cy ? wy1 : wy0;
            #pragma unroll
            for (int cz = 0; cz < 2; ++cz) {
                int zi = cz ? z1 : z0; float wzz = cz ? wz1 : wz0;
                float w = wxx * wyy * wzz;
                usx8 hv = *(const usx8*)(hb + ((size_t)(xi * 32 + yi) * 34 + zi + 1) * 64);
                #pragma unroll
                for (int i = 0; i < 8; ++i) acc[i] = fmaf(w, bf2f(hv[i]), acc[i]);
            }
        }
    }
    float ss = stp[(b * 8 + s) * 2 + 0], ss2 = stp[(b * 8 + s) * 2 + 1];
    float mean = ss * (1.f / 262144.f);
    float rstd = rsqrtf(ss2 * (1.f / 262144.f) - mean * mean + 1e-5f);
    const short* pb = pbuf + (((size_t)(b * CCH)) << 15) + n;
    #pragma unroll
    for (int i = 0; i < 8; ++i) {
        int co = s * 8 + i;
        float* op = out1 + (((size_t)(b * CCH + co)) << 15) + n;
        float pv = bf2f((unsigned short)pb[((size_t)co) << 15]);
        float g = (pv - mean) * rstd * gp[co] + bep[co];
        float sw = g / (1.f + __expf(-g));
        *op = acc[i] + sw;
    }
}

// --------------------------------- launcher ------------------------------------
extern "C" void kernel_launch(void* const* d_in, const int* in_sizes, int n_in,
                              void* d_out, int out_size, void* d_ws, size_t ws_size,
                              hipStream_t stream) {
    const float* feat   = (const float*)d_in[0];
    const float* coords = (const float*)d_in[1];
    const float* w1  = (const float*)d_in[2];
    const float* b1  = (const float*)d_in[3];
    const float* g1  = (const float*)d_in[4];
    const float* be1 = (const float*)d_in[5];
    const float* w2  = (const float*)d_in[6];
    const float* b2  = (const float*)d_in[7];
    const float* g2  = (const float*)d_in[8];
    const float* be2 = (const float*)d_in[9];
    const float* wp  = (const float*)d_in[10];
    const float* bp  = (const float*)d_in[11];
    const float* gp  = (const float*)d_in[12];
    const float* bep = (const float*)d_in[13];

    float* out1 = (float*)d_out;
    float* out2 = out1 + (size_t)BB * CCH * NPT;

    // workspace layout (~216 MB)
    // region0 [0, 134MB): featT bf16 (67MB) -> voxT_mid bf16 (71MB) -> pbuf bf16 (67MB)
    const size_t reg0Bytes = (size_t)BB * NPT * CCH * 4;
    short* featT    = (short*)d_ws;
    short* voxT_mid = (short*)d_ws;
    short* pbuf     = (short*)d_ws;
    short* voxT_in  = (short*)((char*)d_ws + reg0Bytes);
    char* p = (char*)voxT_in + (size_t)BB * VOXB * 2;
    int*   hist   = (int*)p;  p += (size_t)BB * R3 * 4;
    int*   startB = (int*)p;  p += (size_t)BB * R3 * 4;
    int*   base   = (int*)p;  p += (size_t)BB * R3 * 4;
    float* normc = (float*)p; p += (size_t)BB * 3 * NPT * 4;
    int*   vidx  = (int*)p;   p += (size_t)BB * NPT * 4;
    short* wT1   = (short*)p; p += 110592 * 2;
    short* wT2   = (short*)p; p += 110592 * 2;
    float* st1   = (float*)p; p += 256 * 4;
    float* st2   = (float*)p; p += 256 * 4;
    float* stp   = (float*)p; p += 256 * 4;
    float* csum  = (float*)p; p += 64 * 4;
    int*   cmax  = (int*)p;   p += 16 * 4;
    float* scl1  = (float*)p; p += 1024 * 4;
    float* sft1  = (float*)p; p += 1024 * 4;
    float* scl2  = (float*)p; p += 1024 * 4;
    float* sft2  = (float*)p; p += 1024 * 4;

    // fused zeroing: voxT_in pads + hist + st1..cmax block (848 floats)
    k_zero<<<1537, 256, 0, stream>>>(voxT_in, hist, st1);
    k_wprep2<<<864, 256, 0, stream>>>(w1, w2, wT1, wT2);
    k_cstat_sum<<<128, 256, 0, stream>>>(coords, csum);
    k_cstat_max<<<128, 256, 0, stream>>>(coords, csum, cmax);
    k_norm_idx<<<(BB * NPT) / 256, 256, 0, stream>>>(coords, csum, cmax, normc, vidx, hist, out2);
    k_prefix<<<BB, 1024, 0, stream>>>(hist, startB, base);
    k_reorder<<<(BB * NPT) / 64, 256, 0, stream>>>(feat, vidx, base, featT);
    k_vox_accum<<<(BB * R3 * 16) / 256, 256, 0, stream>>>(featT, startB, base, voxT_in);

    // featT dead -> region0 becomes voxT_mid; zero only its z-pads
    k_padzero<<<1024, 256, 0, stream>>>(voxT_mid);

    // conv1 -> voxT_mid holds PRE-GN conv1 output + st1 sums
    k_conv_mfma<false><<<1024, 512, 0, stream>>>(voxT_in, wT1, b1,
                                                 nullptr, nullptr, voxT_mid, st1);
    k_gnprep<<<4, 256, 0, stream>>>(st1, g1, be1, scl1, sft1);
    // conv2: staging applies GN1+swish (tables) -> voxT_in (PRE-GN2), st2 sums
    k_conv_mfma<true><<<1024, 512, 0, stream>>>(voxT_mid, wT2, b2,
                                                scl1, sft1, voxT_in, st2);
    k_gnprep<<<4, 256, 0, stream>>>(st2, g2, be2, scl2, sft2);
    // GN2 apply+swish in place (table-based)
    k_gn_apply_b<<<(BB * R3 * 8) / 256, 256, 0, stream>>>(voxT_in, scl2, sft2);

    // voxT_mid dead -> region0 becomes pbuf
    k_point<<<dim3(NPT / 64, BB), 256, 0, stream>>>(feat, wp, bp, pbuf, stp);

    k_final<<<(BB * NPT) / 32, 256, 0, stream>>>(voxT_in, normc, stp, gp, bep, pbuf, out1);
}

// Round 17
// 696.772 us; speedup vs baseline: 1.2799x; 1.0144x over previous
//
#include <hip/hip_runtime.h>
#include <hip/hip_bf16.h>
#include <math.h>

#define BB   16
#define CCH  64
#define NPT  32768
#define RR   32
#define R3   32768
#define GSZ  262144
#define VOXB 2228224   // 32*32*34*64 bf16 elements per batch (z padded to 34)

typedef __attribute__((ext_vector_type(8))) short bfx8;
typedef __attribute__((ext_vector_type(8))) unsigned short usx8;
typedef __attribute__((ext_vector_type(16))) float f32x16;

__device__ __forceinline__ short f2bf(float f) {
    unsigned u = __builtin_bit_cast(unsigned, f);
    u += 0x7fff + ((u >> 16) & 1);
    return (short)(u >> 16);
}
__device__ __forceinline__ float bf2f(unsigned short s) {
    unsigned u = ((unsigned)s) << 16;
    return __builtin_bit_cast(float, u);
}

// ---------------- block reduction helpers -------------------------------------
__device__ __forceinline__ float blockReduceSumF(float v) {
    __shared__ float sm[16];
    #pragma unroll
    for (int o = 32; o > 0; o >>= 1) v += __shfl_down(v, o);
    __syncthreads();
    if ((threadIdx.x & 63) == 0) sm[threadIdx.x >> 6] = v;
    __syncthreads();
    float s = 0.f;
    int nw = blockDim.x >> 6;
    for (int i = 0; i < nw; ++i) s += sm[i];
    return s;
}

__device__ __forceinline__ float blockReduceMaxF(float v) {
    __shared__ float sm[16];
    #pragma unroll
    for (int o = 32; o > 0; o >>= 1) v = fmaxf(v, __shfl_down(v, o));
    __syncthreads();
    if ((threadIdx.x & 63) == 0) sm[threadIdx.x >> 6] = v;
    __syncthreads();
    float s = sm[0];
    int nw = blockDim.x >> 6;
    for (int i = 1; i < nw; ++i) s = fmaxf(s, sm[i]);
    return s;
}

// ---------------- 0. fused zeroing: voxT_in z-pads + hist + st block -----------
__global__ void k_zero(short* __restrict__ voxTin, int* __restrict__ hist,
                       float* __restrict__ stblk) {
    int t = blockIdx.x * 256 + threadIdx.x;
    if (t < 262144) {               // 16b * 1024xy * 2zp * 8q
        int q = t & 7, zp = (t >> 3) & 1, xy = (t >> 4) & 1023, b = t >> 14;
        int z = zp ? 33 : 0;
        *(int4*)(voxTin + (size_t)b * VOXB + ((size_t)xy * 34 + z) * 64 + q * 8) =
            make_int4(0, 0, 0, 0);
    } else if (t < 262144 + 131072) {   // hist 2MB
        ((int4*)hist)[t - 262144] = make_int4(0, 0, 0, 0);
    } else if (t < 262144 + 131072 + 212) {  // st1,st2,stp,csum,cmax = 848 floats
        ((int4*)stblk)[t - 262144 - 131072] = make_int4(0, 0, 0, 0);
    }
}

// ---------------- 1a. coord partial sums (128 blocks) --------------------------
__global__ void k_cstat_sum(const float* __restrict__ coords, float* __restrict__ csum) {
    int b = blockIdx.x >> 3, seg = blockIdx.x & 7;
    const float* cb = coords + (size_t)b * 3 * NPT;
    int n0 = seg << 12;
    float sx = 0.f, sy = 0.f, sz = 0.f;
    for (int n = n0 + threadIdx.x; n < n0 + 4096; n += 256) {
        sx += cb[n]; sy += cb[NPT + n]; sz += cb[2 * NPT + n];
    }
    sx = blockReduceSumF(sx);
    sy = blockReduceSumF(sy);
    sz = blockReduceSumF(sz);
    if (threadIdx.x == 0) {
        atomicAdd(&csum[b * 4 + 0], sx);
        atomicAdd(&csum[b * 4 + 1], sy);
        atomicAdd(&csum[b * 4 + 2], sz);
    }
}

// ---------------- 1b. coord max distance (128 blocks, int-bits atomicMax) ------
__global__ void k_cstat_max(const float* __restrict__ coords, const float* __restrict__ csum,
                            int* __restrict__ cmax) {
    int b = blockIdx.x >> 3, seg = blockIdx.x & 7;
    const float* cb = coords + (size_t)b * 3 * NPT;
    float mx = csum[b * 4 + 0] * (1.f / NPT);
    float my = csum[b * 4 + 1] * (1.f / NPT);
    float mz = csum[b * 4 + 2] * (1.f / NPT);
    int n0 = seg << 12;
    float mn = 0.f;
    for (int n = n0 + threadIdx.x; n < n0 + 4096; n += 256) {
        float x = cb[n] - mx, y = cb[NPT + n] - my, z = cb[2 * NPT + n] - mz;
        mn = fmaxf(mn, sqrtf(x * x + y * y + z * z));
    }
    mn = blockReduceMaxF(mn);
    if (threadIdx.x == 0) atomicMax(&cmax[b], __float_as_int(mn));
}

// ---------------- 2. normalized coords + voxel idx + histogram + passthrough ---
__global__ void k_norm_idx(const float* __restrict__ coords, const float* __restrict__ csum,
                           const int* __restrict__ cmax,
                           float* __restrict__ normc, int* __restrict__ vidx,
                           int* __restrict__ hist, float* __restrict__ out2) {
    int t = blockIdx.x * 256 + threadIdx.x;
    int b = t >> 15, n = t & 32767;
    float mx = csum[b * 4 + 0] * (1.f / NPT);
    float my = csum[b * 4 + 1] * (1.f / NPT);
    float mz = csum[b * 4 + 2] * (1.f / NPT);
    float scale = 2.f * __int_as_float(cmax[b]);
    const float* cb = coords + (size_t)b * 3 * NPT;
    float x = cb[n], y = cb[NPT + n], z = cb[2 * NPT + n];
    float nx = fminf(fmaxf(((x - mx) / scale + 0.5f) * 32.f, 0.f), 31.f);
    float ny = fminf(fmaxf(((y - my) / scale + 0.5f) * 32.f, 0.f), 31.f);
    float nz = fminf(fmaxf(((z - mz) / scale + 0.5f) * 32.f, 0.f), 31.f);
    float* nb = normc + (size_t)b * 3 * NPT;
    nb[n] = nx; nb[NPT + n] = ny; nb[2 * NPT + n] = nz;
    int vx = (int)rintf(nx), vy = (int)rintf(ny), vz = (int)rintf(nz);
    int v = (vx * 32 + vy) * 32 + vz;
    vidx[t] = v;
    atomicAdd(&hist[(b << 15) + v], 1);
    float* o2 = out2 + (size_t)b * 3 * NPT;
    o2[n] = x; o2[NPT + n] = y; o2[2 * NPT + n] = z;
}

// ---------------- 3. per-batch exclusive prefix over 32768 bins ----------------
__global__ __launch_bounds__(1024) void k_prefix(const int* __restrict__ hist,
                                                 int* __restrict__ startB,
                                                 int* __restrict__ base) {
    int b = blockIdx.x;
    int tid = threadIdx.x;
    const int* h = hist + (b << 15);
    int loc[32];
    int s = 0;
    #pragma unroll
    for (int j = 0; j < 32; ++j) { loc[j] = h[tid * 32 + j]; s += loc[j]; }
    __shared__ int sm[1024];
    sm[tid] = s;
    __syncthreads();
    for (int o = 1; o < 1024; o <<= 1) {
        int v = (tid >= o) ? sm[tid - o] : 0;
        __syncthreads();
        sm[tid] += v;
        __syncthreads();
    }
    int run = (tid ? sm[tid - 1] : 0);
    #pragma unroll
    for (int j = 0; j < 32; ++j) {
        int idx = (b << 15) + tid * 32 + j;
        startB[idx] = run;
        base[idx] = run;
        run += loc[j];
    }
}

// ---------------- 4. reorder: feat [b][c][n] f32 -> featT [b][slot][c] bf16 ----
__global__ __launch_bounds__(256) void k_reorder(const float* __restrict__ feat,
                                                 const int* __restrict__ vidx,
                                                 int* __restrict__ base,
                                                 short* __restrict__ featT) {
    __shared__ float tile[64][65];
    __shared__ int sslot[64];
    int blk = blockIdx.x;             // 8192 = 16 b * 512
    int b = blk >> 9;
    int n0 = (blk & 511) << 6;
    int tid = threadIdx.x;
    const float* fb = feat + ((size_t)b << 21);
    for (int e = tid; e < 64 * 16; e += 256) {
        int c = e >> 4, n4 = e & 15;
        float4 v4 = *(const float4*)(fb + ((size_t)c << 15) + n0 + n4 * 4);
        tile[c][n4 * 4 + 0] = v4.x; tile[c][n4 * 4 + 1] = v4.y;
        tile[c][n4 * 4 + 2] = v4.z; tile[c][n4 * 4 + 3] = v4.w;
    }
    if (tid < 64) {
        int v = vidx[(b << 15) + n0 + tid];
        sslot[tid] = atomicAdd(&base[(b << 15) + v], 1);
    }
    __syncthreads();
    int p = tid >> 2, q = tid & 3;    // 4 threads/point, 16 ch each
    int slot = sslot[p];
    short* dst = featT + (((size_t)((b << 15) + slot)) << 6) + q * 16;
    unsigned pk[8];
    #pragma unroll
    for (int k = 0; k < 8; ++k) {
        unsigned lo16 = (unsigned short)f2bf(tile[q * 16 + 2 * k][p]);
        unsigned hi16 = (unsigned short)f2bf(tile[q * 16 + 2 * k + 1][p]);
        pk[k] = lo16 | (hi16 << 16);
    }
    *(int4*)dst = make_int4(pk[0], pk[1], pk[2], pk[3]);
    *(int4*)(dst + 8) = make_int4(pk[4], pk[5], pk[6], pk[7]);
}

// ---------------- 5. voxel accumulate + divide + bf16 padded layout ------------
__global__ void k_vox_accum(const short* __restrict__ featT, const int* __restrict__ startB,
                            const int* __restrict__ base, short* __restrict__ vout) {
    int t = blockIdx.x * 256 + threadIdx.x;   // over B*R3*16
    int lane4 = t & 15;
    int v = (t >> 4) & 32767;
    int b = t >> 19;
    int start = startB[(b << 15) + v];
    int end   = base[(b << 15) + v];
    float4 acc = make_float4(0.f, 0.f, 0.f, 0.f);
    const short* fT = featT + (((size_t)b << 15) << 6) + lane4 * 4;
    for (int p = start; p < end; ++p) {
        short4 hv = *(const short4*)(fT + ((size_t)p << 6));
        acc.x += bf2f((unsigned short)hv.x);
        acc.y += bf2f((unsigned short)hv.y);
        acc.z += bf2f((unsigned short)hv.z);
        acc.w += bf2f((unsigned short)hv.w);
    }
    float rc = 1.f / fmaxf((float)(end - start), 1.f);
    short4 pk;
    pk.x = f2bf(acc.x * rc); pk.y = f2bf(acc.y * rc);
    pk.z = f2bf(acc.z * rc); pk.w = f2bf(acc.w * rc);
    *(short4*)(vout + (size_t)b * VOXB + ((size_t)(v >> 5) * 34 + (v & 31) + 1) * 64 + lane4 * 4) = pk;
}

// ---------------- 6. zero only the z-pad slices of a padded volume -------------
__global__ void k_padzero(short* __restrict__ v) {
    int t = blockIdx.x * 256 + threadIdx.x;   // 262144 = 16b * 1024xy * 2zp * 8q
    int q = t & 7, zp = (t >> 3) & 1, xy = (t >> 4) & 1023, b = t >> 14;
    int z = zp ? 33 : 0;
    *(int4*)(v + (size_t)b * VOXB + ((size_t)xy * 34 + z) * 64 + q * 8) = make_int4(0, 0, 0, 0);
}

// ---------------- 7. weight transpose x2: [co][ci][27] f32 -> [k][co][ci] bf16 -
__global__ void k_wprep2(const float* __restrict__ w1, const float* __restrict__ w2,
                         short* __restrict__ wT1, short* __restrict__ wT2) {
    int e = blockIdx.x * 256 + threadIdx.x;   // 2 * 110592
    const float* w = (e < 110592) ? w1 : w2;
    short* o = (e < 110592) ? wT1 : wT2;
    int ee = (e < 110592) ? e : e - 110592;
    int ci = ee & 63, co = (ee >> 6) & 63, k = ee >> 12;
    o[ee] = f2bf(w[(size_t)(co * 64 + ci) * 27 + k]);
}

// ---------------- 7b. GN affine prep: st sums -> per-(b,c) scale/shift ---------
__global__ void k_gnprep(const float* __restrict__ st, const float* __restrict__ g,
                         const float* __restrict__ be,
                         float* __restrict__ scl, float* __restrict__ sft) {
    int t = blockIdx.x * 256 + threadIdx.x;   // 1024 = 16 b * 64 c
    int b = t >> 6, c = t & 63, cg = c >> 3;
    float s = st[(b * 8 + cg) * 2 + 0], s2 = st[(b * 8 + cg) * 2 + 1];
    float mean = s * (1.f / 262144.f);
    float rstd = rsqrtf(s2 * (1.f / 262144.f) - mean * mean + 1e-5f);
    float gm = g[c];
    scl[t] = gm * rstd;
    sft[t] = be[c] - mean * gm * rstd;
}

// ---------------- 8. MFMA implicit-GEMM conv (r8 shape), FUSE via tables -------
// 512 threads = 8 waves = (2 co-halves x 4 x-lines). Per wave: acc[4] f32x16
// (64 AGPR) -> 16 waves/CU resident. FUSE: apply precomputed per-(b,c)
// scale/shift + swish to input during staging (conv2). Epilogue GN stats -> st.
template<bool FUSE>
__global__ __launch_bounds__(512, 4) void k_conv_mfma(
    const short* __restrict__ vin, const short* __restrict__ wT,
    const float* __restrict__ bias,
    const float* __restrict__ scl, const float* __restrict__ sft,
    short* __restrict__ vout, float* __restrict__ st)
{
    __shared__ short lds[36 * 1088];      // 78336 B
    __shared__ float sred[8][2];
    int bid = blockIdx.x;                 // 1024 = 8 xcd * 2 b * 64 tiles
    int xcd = bid & 7, sub = bid >> 3;
    int b = (xcd << 1) | (sub >> 6);
    int tile = sub & 63;
    int x0 = (tile >> 3) << 2, y0 = (tile & 7) << 2;
    int tid = threadIdx.x;
    int wv8 = tid >> 6;
    int cb = wv8 & 1, xl = wv8 >> 1;      // co-half, x-line
    int l = tid & 63, lo = l & 31, hi = l >> 5;
    const short* vb = vin + (size_t)b * VOXB;
    int xo = x0 + xl;
    if (tid < 16) ((float*)sred)[tid] = 0.f;

    f32x16 acc[4];
    #pragma unroll
    for (int j = 0; j < 4; ++j)
        #pragma unroll
        for (int i = 0; i < 16; ++i) acc[j][i] = 0.f;

    #pragma unroll
    for (int h = 0; h < 2; ++h) {
        if (h) __syncthreads();
        for (int e = tid; e < 4896; e += 512) {
            int line = e / 136, r = e - line * 136;
            int z = r >> 2, q = r & 3;
            int xx = line / 6, yy = line - xx * 6;
            int xi = x0 + xx - 1, yi = y0 + yy - 1;
            bool inb = ((unsigned)xi < 32u) && ((unsigned)yi < 32u);
            int4 v = make_int4(0, 0, 0, 0);
            if (inb)
                v = *(const int4*)(vb + ((size_t)(xi * 32 + yi) * 34 + z) * 64 + h * 32 + q * 8);
            if (FUSE) {
                if (inb && z >= 1 && z <= 32) {
                    int ci0 = (b << 6) + h * 32 + q * 8;
                    float4 sa = *(const float4*)(scl + ci0);
                    float4 sb = *(const float4*)(scl + ci0 + 4);
                    float4 fa = *(const float4*)(sft + ci0);
                    float4 fb = *(const float4*)(sft + ci0 + 4);
                    float sv[8] = {sa.x, sa.y, sa.z, sa.w, sb.x, sb.y, sb.z, sb.w};
                    float fv[8] = {fa.x, fa.y, fa.z, fa.w, fb.x, fb.y, fb.z, fb.w};
                    unsigned short* hv = (unsigned short*)&v;
                    #pragma unroll
                    for (int i = 0; i < 8; ++i) {
                        float g = fmaf(bf2f(hv[i]), sv[i], fv[i]);
                        float sw = g / (1.f + __expf(-g));
                        hv[i] = (unsigned short)f2bf(sw);
                    }
                }
            }
            int dst = line * 1088 + z * 32 + ((q * 8) ^ ((z & 3) << 3));
            *(int4*)(lds + dst) = v;
        }
        __syncthreads();
        const short* wbase = wT + lo * 64 + h * 32 + hi * 8 + cb * 2048;
        #pragma unroll
        for (int dx = 0; dx < 3; ++dx) {
            const short* ldsx = lds + ((xl + dx) * 6) * 1088;
            #pragma unroll
            for (int dz = 0; dz < 3; ++dz) {
                int zz = lo + dz;
                int swz = (zz & 3) << 3;
                const short* bcol = ldsx + zz * 32;
                #pragma unroll
                for (int s = 0; s < 2; ++s) {
                    int slot = (s * 16 + hi * 8) ^ swz;
                    const short* wt0 = wbase + (dx * 9 + dz) * 4096 + s * 16;
                    bfx8 w0 = *(const bfx8*)(wt0);
                    bfx8 w1 = *(const bfx8*)(wt0 + 3 * 4096);
                    bfx8 w2 = *(const bfx8*)(wt0 + 6 * 4096);
                    #pragma unroll
                    for (int L = 0; L < 6; ++L) {
                        bfx8 bv = *(const bfx8*)(bcol + L * 1088 + slot);
                        if (L <= 3)
                            acc[L] = __builtin_amdgcn_mfma_f32_32x32x16_bf16(w0, bv, acc[L], 0, 0, 0);
                        if (L >= 1 && L <= 4)
                            acc[L-1] = __builtin_amdgcn_mfma_f32_32x32x16_bf16(w1, bv, acc[L-1], 0, 0, 0);
                        if (L >= 2)
                            acc[L-2] = __builtin_amdgcn_mfma_f32_32x32x16_bf16(w2, bv, acc[L-2], 0, 0, 0);
                    }
                }
            }
        }
    }

    // epilogue: bias + bf16 store + fused GN partial sums (this wave's co-half)
    float gs[4], gs2[4];
    #pragma unroll
    for (int g = 0; g < 4; ++g) { gs[g] = 0.f; gs2[g] = 0.f; }
    short* ob = vout + (size_t)b * VOXB;
    #pragma unroll
    for (int j = 0; j < 4; ++j) {
        size_t rb = ((size_t)(xo * 32 + y0 + j) * 34 + 1 + lo) * 64;
        #pragma unroll
        for (int q = 0; q < 4; ++q) {
            int co0 = cb * 32 + hi * 4 + q * 8;
            float v0 = acc[j][q * 4 + 0] + bias[co0 + 0];
            float v1 = acc[j][q * 4 + 1] + bias[co0 + 1];
            float v2 = acc[j][q * 4 + 2] + bias[co0 + 2];
            float v3 = acc[j][q * 4 + 3] + bias[co0 + 3];
            gs[q] += v0 + v1 + v2 + v3;
            gs2[q] += v0 * v0 + v1 * v1 + v2 * v2 + v3 * v3;
            short4 pk;
            pk.x = f2bf(v0); pk.y = f2bf(v1); pk.z = f2bf(v2); pk.w = f2bf(v3);
            *(short4*)(ob + rb + co0) = pk;
        }
    }
    #pragma unroll
    for (int q = 0; q < 4; ++q) {
        float s = gs[q], s2 = gs2[q];
        #pragma unroll
        for (int o = 32; o > 0; o >>= 1) { s += __shfl_down(s, o); s2 += __shfl_down(s2, o); }
        if (l == 0) { atomicAdd(&sred[cb * 4 + q][0], s); atomicAdd(&sred[cb * 4 + q][1], s2); }
    }
    __syncthreads();
    if (tid < 8) {
        atomicAdd(&st[((b << 3) + tid) * 2 + 0], sred[tid][0]);
        atomicAdd(&st[((b << 3) + tid) * 2 + 1], sred[tid][1]);
    }
}

// ---------------- 9. GN apply + swish (tables), in place on padded volume ------
__global__ void k_gn_apply_b(short* __restrict__ v, const float* __restrict__ scl,
                             const float* __restrict__ sft) {
    int e = blockIdx.x * 256 + threadIdx.x;   // over 16*32768*8
    int cg = e & 7, vx = (e >> 3) & 32767, b = e >> 18;
    int ci0 = (b << 6) + cg * 8;
    float4 sa = *(const float4*)(scl + ci0);
    float4 sb = *(const float4*)(scl + ci0 + 4);
    float4 fa = *(const float4*)(sft + ci0);
    float4 fb = *(const float4*)(sft + ci0 + 4);
    float sv[8] = {sa.x, sa.y, sa.z, sa.w, sb.x, sb.y, sb.z, sb.w};
    float fv[8] = {fa.x, fa.y, fa.z, fa.w, fb.x, fb.y, fb.z, fb.w};
    short* p = v + (size_t)b * VOXB + ((size_t)(vx >> 5) * 34 + (vx & 31) + 1) * 64 + cg * 8;
    usx8 hv = *(const usx8*)p;
    usx8 ov;
    #pragma unroll
    for (int i = 0; i < 8; ++i) {
        float g = fmaf(bf2f(hv[i]), sv[i], fv[i]);
        float sw = g / (1.f + __expf(-g));
        ov[i] = (unsigned short)f2bf(sw);
    }
    *(usx8*)p = ov;
}

// ---------------- 10. point GEMM -> bf16 pre-GN scratch + fused GN stats -------
__global__ __launch_bounds__(256) void k_point(const float* __restrict__ feat,
                                               const float* __restrict__ wp,
                                               const float* __restrict__ bp,
                                               short* __restrict__ pbuf,
                                               float* __restrict__ stp) {
    __shared__ float s_f[64][64];
    __shared__ float s_w[64][68];
    __shared__ float sred[8][2];
    int nblk = blockIdx.x * 64;
    int b = blockIdx.y;
    int tid = threadIdx.x;
    if (tid < 16) ((float*)sred)[tid] = 0.f;
    const float* fb = feat + (((size_t)b * CCH) << 15);
    for (int e = tid; e < 64 * 64; e += 256) {
        int c = e >> 6, nn = e & 63;
        s_f[c][nn] = fb[(((size_t)c) << 15) + nblk + nn];
        s_w[nn][c] = wp[e];
    }
    __syncthreads();
    int o0 = (tid >> 4) << 2;
    int n0 = (tid & 15) << 2;
    float acc[4][4] = {{0.f}};
    for (int c = 0; c < 64; ++c) {
        float4 fv = *(const float4*)&s_f[c][n0];
        float4 wv = *(const float4*)&s_w[c][o0];
        float fvv[4] = {fv.x, fv.y, fv.z, fv.w};
        float wvv[4] = {wv.x, wv.y, wv.z, wv.w};
        #pragma unroll
        for (int j = 0; j < 4; ++j)
            #pragma unroll
            for (int i = 0; i < 4; ++i) acc[j][i] += wvv[j] * fvv[i];
    }
    float s = 0.f, s2 = 0.f;
    #pragma unroll
    for (int j = 0; j < 4; ++j) {
        float bb = bp[o0 + j];
        short* op = pbuf + (((size_t)(b * CCH + o0 + j)) << 15) + nblk + n0;
        short4 pk;
        float v0 = acc[j][0] + bb, v1 = acc[j][1] + bb;
        float v2 = acc[j][2] + bb, v3 = acc[j][3] + bb;
        s += v0 + v1 + v2 + v3;
        s2 += v0 * v0 + v1 * v1 + v2 * v2 + v3 * v3;
        pk.x = f2bf(v0); pk.y = f2bf(v1); pk.z = f2bf(v2); pk.w = f2bf(v3);
        *(short4*)op = pk;
    }
    int g = o0 >> 3;
    atomicAdd(&sred[g][0], s);
    atomicAdd(&sred[g][1], s2);
    __syncthreads();
    if (tid < 8) {
        atomicAdd(&stp[(b * 8 + tid) * 2 + 0], sred[tid][0]);
        atomicAdd(&stp[(b * 8 + tid) * 2 + 1], sred[tid][1]);
    }
}

// ---------------- 11. final: devox gather + point GN/swish + coalesced store ---
__global__ __launch_bounds__(256) void k_final(
    const short* __restrict__ h, const float* __restrict__ normc,
    const float* __restrict__ stp, const float* __restrict__ gp,
    const float* __restrict__ bep, const short* __restrict__ pbuf,
    float* __restrict__ out1) {
    __shared__ float sm[64][33];
    int tid = threadIdx.x;
    int s = tid & 7, pp = tid >> 3;
    int blk = blockIdx.x;              // 16384 = 16 b * 1024
    int b = blk >> 10;
    int n0 = (blk & 1023) << 5;
    int n = n0 + pp;
    const float* nb = normc + (size_t)b * 3 * NPT;
    float nx = nb[n], ny = nb[NPT + n], nz = nb[2 * NPT + n];
    float fxf = floorf(nx), fyf = floorf(ny), fzf = floorf(nz);
    float fx = nx - fxf, fy = ny - fyf, fz = nz - fzf;
    int x0 = (int)fxf; x0 = x0 < 31 ? x0 : 31;
    int y0 = (int)fyf; y0 = y0 < 31 ? y0 : 31;
    int z0 = (int)fzf; z0 = z0 < 31 ? z0 : 31;
    int x1 = x0 + 1 < 31 ? x0 + 1 : 31;
    int y1 = y0 + 1 < 31 ? y0 + 1 : 31;
    int z1 = z0 + 1 < 31 ? z0 + 1 : 31;
    float wx0 = 1.f - fx, wx1 = fx, wy0 = 1.f - fy, wy1 = fy, wz0 = 1.f - fz, wz1 = fz;
    const short* hb = h + (size_t)b * VOXB + s * 8;
    float acc[8];
    #pragma unroll
    for (int i = 0; i < 8; ++i) acc[i] = 0.f;
    #pragma unroll
    for (int cx = 0; cx < 2; ++cx) {
        int xi = cx ? x1 : x0; float wxx = cx ? wx1 : wx0;
        #pragma unroll
        for (int cy = 0; cy < 2; ++cy) {
            int yi = cy ? y1 : y0; float wyy = cy ? wy1 : wy0;
            #pragma unroll
            for (int cz = 0; cz < 2; ++cz) {
                int zi = cz ? z1 : z0; float wzz = cz ? wz1 : wz0;
                float w = wxx * wyy * wzz;
                usx8 hv = *(const usx8*)(hb + ((size_t)(xi * 32 + yi) * 34 + zi + 1) * 64);
                #pragma unroll
                for (int i = 0; i < 8; ++i) acc[i] = fmaf(w, bf2f(hv[i]), acc[i]);
            }
        }
    }
    float ss = stp[(b * 8 + s) * 2 + 0], ss2 = stp[(b * 8 + s) * 2 + 1];
    float mean = ss * (1.f / 262144.f);
    float rstd = rsqrtf(ss2 * (1.f / 262144.f) - mean * mean + 1e-5f);
    const short* pb = pbuf + (((size_t)(b * CCH)) << 15) + n;
    #pragma unroll
    for (int i = 0; i < 8; ++i) {
        int co = s * 8 + i;
        float pv = bf2f((unsigned short)pb[((size_t)co) << 15]);
        float g = (pv - mean) * rstd * gp[co] + bep[co];
        float sw = g / (1.f + __expf(-g));
        sm[co][pp] = acc[i] + sw;
    }
    __syncthreads();
    // coalesced store: 4 threads per co, each 8 contiguous floats (2x float4)
    int co = tid >> 2, q = (tid & 3) << 3;
    float r0 = sm[co][q + 0], r1 = sm[co][q + 1], r2 = sm[co][q + 2], r3 = sm[co][q + 3];
    float r4 = sm[co][q + 4], r5 = sm[co][q + 5], r6 = sm[co][q + 6], r7 = sm[co][q + 7];
    float* op = out1 + (((size_t)(b * CCH + co)) << 15) + n0 + q;
    *(float4*)op = make_float4(r0, r1, r2, r3);
    *(float4*)(op + 4) = make_float4(r4, r5, r6, r7);
}

// --------------------------------- launcher ------------------------------------
extern "C" void kernel_launch(void* const* d_in, const int* in_sizes, int n_in,
                              void* d_out, int out_size, void* d_ws, size_t ws_size,
                              hipStream_t stream) {
    const float* feat   = (const float*)d_in[0];
    const float* coords = (const float*)d_in[1];
    const float* w1  = (const float*)d_in[2];
    const float* b1  = (const float*)d_in[3];
    const float* g1  = (const float*)d_in[4];
    const float* be1 = (const float*)d_in[5];
    const float* w2  = (const float*)d_in[6];
    const float* b2  = (const float*)d_in[7];
    const float* g2  = (const float*)d_in[8];
    const float* be2 = (const float*)d_in[9];
    const float* wp  = (const float*)d_in[10];
    const float* bp  = (const float*)d_in[11];
    const float* gp  = (const float*)d_in[12];
    const float* bep = (const float*)d_in[13];

    float* out1 = (float*)d_out;
    float* out2 = out1 + (size_t)BB * CCH * NPT;

    // workspace layout (~216 MB)
    // region0 [0, 134MB): featT bf16 (67MB) -> voxT_mid bf16 (71MB) -> pbuf bf16 (67MB)
    const size_t reg0Bytes = (size_t)BB * NPT * CCH * 4;
    short* featT    = (short*)d_ws;
    short* voxT_mid = (short*)d_ws;
    short* pbuf     = (short*)d_ws;
    short* voxT_in  = (short*)((char*)d_ws + reg0Bytes);
    char* p = (char*)voxT_in + (size_t)BB * VOXB * 2;
    int*   hist   = (int*)p;  p += (size_t)BB * R3 * 4;
    int*   startB = (int*)p;  p += (size_t)BB * R3 * 4;
    int*   base   = (int*)p;  p += (size_t)BB * R3 * 4;
    float* normc = (float*)p; p += (size_t)BB * 3 * NPT * 4;
    int*   vidx  = (int*)p;   p += (size_t)BB * NPT * 4;
    short* wT1   = (short*)p; p += 110592 * 2;
    short* wT2   = (short*)p; p += 110592 * 2;
    float* st1   = (float*)p; p += 256 * 4;
    float* st2   = (float*)p; p += 256 * 4;
    float* stp   = (float*)p; p += 256 * 4;
    float* csum  = (float*)p; p += 64 * 4;
    int*   cmax  = (int*)p;   p += 16 * 4;
    float* scl1  = (float*)p; p += 1024 * 4;
    float* sft1  = (float*)p; p += 1024 * 4;
    float* scl2  = (float*)p; p += 1024 * 4;
    float* sft2  = (float*)p; p += 1024 * 4;

    // fused zeroing: voxT_in pads + hist + st1..cmax block (848 floats)
    k_zero<<<1537, 256, 0, stream>>>(voxT_in, hist, st1);
    k_wprep2<<<864, 256, 0, stream>>>(w1, w2, wT1, wT2);
    k_cstat_sum<<<128, 256, 0, stream>>>(coords, csum);
    k_cstat_max<<<128, 256, 0, stream>>>(coords, csum, cmax);
    k_norm_idx<<<(BB * NPT) / 256, 256, 0, stream>>>(coords, csum, cmax, normc, vidx, hist, out2);
    k_prefix<<<BB, 1024, 0, stream>>>(hist, startB, base);
    k_reorder<<<(BB * NPT) / 64, 256, 0, stream>>>(feat, vidx, base, featT);
    k_vox_accum<<<(BB * R3 * 16) / 256, 256, 0, stream>>>(featT, startB, base, voxT_in);

    // featT dead -> region0 becomes voxT_mid; zero only its z-pads
    k_padzero<<<1024, 256, 0, stream>>>(voxT_mid);

    // conv1 -> voxT_mid holds PRE-GN conv1 output + st1 sums
    k_conv_mfma<false><<<1024, 512, 0, stream>>>(voxT_in, wT1, b1,
                                                 nullptr, nullptr, voxT_mid, st1);
    k_gnprep<<<4, 256, 0, stream>>>(st1, g1, be1, scl1, sft1);
    // conv2: staging applies GN1+swish (tables) -> voxT_in (PRE-GN2), st2 sums
    k_conv_mfma<true><<<1024, 512, 0, stream>>>(voxT_mid, wT2, b2,
                                                scl1, sft1, voxT_in, st2);
    k_gnprep<<<4, 256, 0, stream>>>(st2, g2, be2, scl2, sft2);
    // GN2 apply+swish in place (table-based)
    k_gn_apply_b<<<(BB * R3 * 8) / 256, 256, 0, stream>>>(voxT_in, scl2, sft2);

    // voxT_mid dead -> region0 becomes pbuf
    k_point<<<dim3(NPT / 64, BB), 256, 0, stream>>>(feat, wp, bp, pbuf, stp);

    k_final<<<(BB * NPT) / 32, 256, 0, stream>>>(voxT_in, normc, stp, gp, bep, pbuf, out1);
}